// Round 7
// baseline (4145.663 us; speedup 1.0000x reference)
//
#include <hip/hip_runtime.h>

typedef unsigned int u32;
typedef unsigned short u16;
typedef unsigned long long u64;
typedef __attribute__((ext_vector_type(8))) short short8;
typedef __attribute__((ext_vector_type(4))) float floatx4;
typedef __attribute__((ext_vector_type(4))) int intx4;

#define TT 1024
#define BIN_OFF 6553600
#define ACT_OFF 7864320

__device__ __forceinline__ u16 f2b(float f) {
  u32 u = __builtin_bit_cast(u32, f);
  u += 0x7fffu + ((u >> 16) & 1u);
  return (u16)(u >> 16);
}
__device__ __forceinline__ float sigmf(float x) { return 1.0f / (1.0f + __expf(-x)); }
__device__ __forceinline__ float tanhfast(float x) {
  x = fminf(x, 15.0f);
  float e = __expf(2.0f * x);
  return (e - 1.0f) / (e + 1.0f);
}

// ---------------- prep ----------------

__global__ void k_zero4(u32* __restrict__ p) {
  if (threadIdx.x < 4) p[threadIdx.x] = 0;
}
// absmax of x / W_hh / W_ih -> am[0..2] (uint-ordered positive floats). grid 2048x256
__global__ void k_amax(const float* __restrict__ x, const float* __restrict__ wih,
                       const float* __restrict__ whh, u32* __restrict__ am) {
  __shared__ float red[256];
  const int tid = threadIdx.x;
  int b = blockIdx.x;
  const float* src; size_t n; int sec, b0, nb;
  if (b < 1920)      { src = x;   n = 5636096; sec = 0; b0 = 0;    nb = 1920; }
  else if (b < 2016) { src = whh; n = 262144;  sec = 1; b0 = 1920; nb = 96; }
  else               { src = wih; n = 44032;   sec = 2; b0 = 2016; nb = 32; }
  float m = 0.f;
  for (size_t i = (size_t)(b - b0) * 256 + tid; i < n; i += (size_t)nb * 256)
    m = fmaxf(m, fabsf(src[i]));
  red[tid] = m;
  __syncthreads();
  for (int s = 128; s > 0; s >>= 1) {
    if (tid < s) red[tid] = fmaxf(red[tid], red[tid + s]);
    __syncthreads();
  }
  if (tid == 0) atomicMax(&am[sec], __float_as_uint(red[0]));
}
// bias = b_ih + b_hh.  grid 4 x 256
__global__ void k_prep_bias(const float* __restrict__ a, const float* __restrict__ b,
                            float* __restrict__ o) {
  int i = blockIdx.x * 256 + threadIdx.x;
  o[i] = a[i] + b[i];
}
// i8 weight fragments for transposed MFMA (A = W). Per wave w: 40 frags,
// F = tile*5 + c (tile = gate*2+ht, c: 0..3 h-chunks, 4 = x-chunk).
// A-frag: lane l: n = gate*256+w*32+ht*16+(l&15); k = (l>>4)*16 + jq*4 + b.
// x-chunk slots: k<43 = W_ih/sn_x; k=43 coarse-bias code; k=44 fine-bias code.
// grid 320 x 256 (81920 dwords)
__global__ void k_prep_wq(const float* __restrict__ wih, const float* __restrict__ whh,
                          const float* __restrict__ bias, const u32* __restrict__ am,
                          int* __restrict__ wq, float* __restrict__ sbuf) {
  u32 idx = blockIdx.x * 256 + threadIdx.x;
  const float xmax = fmaxf(__uint_as_float(am[0]), 1e-8f);
  const float whm  = fmaxf(__uint_as_float(am[1]), 1e-8f);
  const float wxm  = fmaxf(__uint_as_float(am[2]), 1e-8f);
  const float sn_h = whm / 127.0f, sn_x = wxm / 127.0f;
  const float sx = xmax / 127.0f;
  if (idx == 0) {
    sbuf[0] = sn_h / 127.0f;           // A_h
    sbuf[1] = sn_x * sx;               // A_x
    sbuf[2] = sn_x * sx / 254.0f;      // A_x2
  }
  int jq = idx & 3;
  int lane = (idx >> 2) & 63;
  u32 wf = idx >> 8;                   // w*40 + F, < 320
  int F = wf % 40, w = wf / 40;
  int tile = F / 5, c = F % 5;
  int gate = tile >> 1, ht = tile & 1;
  int l15 = lane & 15, kq = lane >> 4;
  int n = gate * 256 + w * 32 + ht * 16 + l15;
  u32 out = 0;
#pragma unroll
  for (int b = 0; b < 4; ++b) {
    int kl = kq * 16 + jq * 4 + b;
    float q = 0.f;
    if (c < 4) {
      q = rintf(whh[n * 256 + c * 64 + kl] / sn_h);
    } else {
      if (kl < 43) q = rintf(wih[n * 43 + kl] / sn_x);
      else if (kl == 43) {
        float u1 = sn_x * xmax;
        q = fminf(fmaxf(rintf(bias[n] / u1), -127.f), 127.f);
      } else if (kl == 44) {
        float u1 = sn_x * xmax;
        float qc = fminf(fmaxf(rintf(bias[n] / u1), -127.f), 127.f);
        q = rintf((bias[n] - qc * u1) / (u1 / 254.0f));
      }
    }
    q = fminf(fmaxf(q, -127.f), 127.f);
    int qi = (int)q;
    out |= ((u32)(qi & 255)) << (8 * b);
  }
  wq[idx] = (int)out;
}
// i8 x-images per (bg,t): main (scale sx) + residual (scale sx/254), each 1KB.
// dword (k16,m,jq): bytes k = k16*16+jq*4+b; k<35: x[t]; 35..42: x[t-1]; 43/44: bias
// const slots (main:127/0, res:0/127).  grid 16384 x 256 (4,194,304 dwords)
__global__ void k_prep_xq(const float* __restrict__ x, const u32* __restrict__ am,
                          int* __restrict__ xq) {
  u32 idx = blockIdx.x * 256 + threadIdx.x;
  const float xmax = fmaxf(__uint_as_float(am[0]), 1e-8f);
  const float sx = xmax / 127.0f, sr = sx / 254.0f;
  u32 unit = idx >> 9;
  u32 rem = idx & 511;
  int res = (rem >> 8) & 1;
  int t8 = rem & 255;
  int k16 = t8 >> 6, m = (t8 >> 2) & 15, jq = t8 & 3;
  int bg = unit >> 10, t = unit & 1023;
  u32 out = 0;
#pragma unroll
  for (int b = 0; b < 4; ++b) {
    int k = k16 * 16 + jq * 4 + b;
    int q = 0;
    if (k < 43) {
      float xv = 0.f;
      if (k < 35) xv = x[((size_t)(bg * 16 + m) * TT + t) * 43 + k];
      else if (t > 0) xv = x[((size_t)(bg * 16 + m) * TT + (t - 1)) * 43 + k];
      float q1 = fminf(fmaxf(rintf(xv / sx), -127.f), 127.f);
      if (!res) q = (int)q1;
      else q = (int)fminf(fmaxf(rintf((xv - sx * q1) / sr), -127.f), 127.f);
    } else if (k == 43) q = res ? 0 : 127;
    else if (k == 44) q = res ? 127 : 0;
    out |= ((u32)(q & 255)) << (8 * b);
  }
  xq[idx] = (int)out;
}
// W_afc1 (256x256) and W_aout padded to 16x256.  grid 272 x 256
__global__ void k_prep_afc(const float* __restrict__ wafc1, const float* __restrict__ waout,
                           u16* __restrict__ ob1, u16* __restrict__ ob2) {
  int r = blockIdx.x, k = threadIdx.x;
  if (r < 256) ob1[r * 256 + k] = f2b(wafc1[r * 256 + k]);
  else {
    int y = r - 256;
    ob2[y * 256 + k] = f2b(y < 8 ? waout[y * 256 + k] : 0.f);
  }
}
// Wcb[64][288]: rows 0..49 W_cont, 50..59 W_bin.  grid 64 x 288
__global__ void k_prep_wcb(const float* __restrict__ wcont, const float* __restrict__ wbin,
                           u16* __restrict__ o) {
  int nrow = blockIdx.x, k = threadIdx.x;
  float v = 0.f;
  if (k < 264) {
    if (nrow < 50) v = wcont[nrow * 264 + k];
    else if (nrow < 60) v = wbin[(nrow - 50) * 264 + k];
  }
  o[nrow * 288 + k] = f2b(v);
}

// ---------------- LSTM scan v7: self-contained i8, transposed ----------------
// 8 WGs x 512 thr; WG owns batch rows [16g,16g+16), ALL 1024 gate cols.
// Transposed GEMM: gates[n][m] = sum_k Wq[n,k]*xhq[m,k], mfma_i32_16x16x64_i8,
// A = weights (40 frags/wave, register/AGPR-resident), B = [x|h]^T.
// h-image in LDS (stride-5-dword chunks: 2-way banks, free). x main+residual
// i8 images streamed from global (prepped), bias folded into const slots.
// Zero cross-WG communication; one barrier/step.
__global__ __launch_bounds__(512, 2)
void k_scan7(const int* wq_, const int* __restrict__ xq,
             const float* __restrict__ sb, u16* __restrict__ hs) {
  __shared__ u32 bimg[2 * 1280];        // 2 parities x 256 chunks x 5 dwords (10KB)
  const int tid = threadIdx.x;
  const int w = tid >> 6, lane = tid & 63;
  const int l15 = lane & 15, kq = lane >> 4;
  const int bg = blockIdx.x;
  const int b0 = bg * 16;

  for (int i = tid; i < 2560; i += 512) bimg[i] = 0;

  intx4 wfr[40];
  {
    const intx4* wp = (const intx4*)wq_ + (size_t)(w * 40) * 64 + lane;
#pragma unroll
    for (int F = 0; F < 40; ++F) wfr[F] = wp[(size_t)F * 64];
  }
  const float A_h = sb[0], A_x = sb[1], A_x2 = sb[2];

  const int* xu = xq + (size_t)bg * 1024 * 512;      // 512 dwords per (bg,t)
  const int xoff = kq * 64 + l15 * 4;                // dword offset in 1KB image
  intx4 xa = *(const intx4*)(xu + xoff);
  intx4 xr = *(const intx4*)(xu + 256 + xoff);

  // writer chunk/slot (per ht): chunk = (w>>1)*64 + ((2w+ht)&3)*16 + l15, slot kq
  int wi[2];
#pragma unroll
  for (int ht = 0; ht < 2; ++ht)
    wi[ht] = ((w >> 1) * 64 + ((w * 2 + ht) & 3) * 16 + l15) * 5 + kq;
  // reader chunk base (per h-chunk c): (c*64 + kq*16 + l15)*5
  const int rb = (kq * 16 + l15) * 5;
  u16* hsp = hs + (size_t)(b0 + l15) * TT * 256 + w * 32 + kq * 4;

  float c_st[8];
#pragma unroll
  for (int i = 0; i < 8; ++i) c_st[i] = 0.f;
  u64 h64[2] = {0, 0};
  __syncthreads();

  for (int t = 0; t < TT; ++t) {
    const int cur = t & 1, nxt = cur ^ 1;
    if (t > 0) {  // deferred hs stores of h_{t-1} (drain overlaps compute)
      *(u64*)(hsp + (size_t)(t - 1) * 256) = h64[0];
      *(u64*)(hsp + (size_t)(t - 1) * 256 + 16) = h64[1];
    }
    intx4 xaN = xa, xrN = xr;
    if (t + 1 < TT) {  // prefetch next x frags
      xaN = *(const intx4*)(xu + (size_t)(t + 1) * 512 + xoff);
      xrN = *(const intx4*)(xu + (size_t)(t + 1) * 512 + 256 + xoff);
    }
    intx4 bh[4];
#pragma unroll
    for (int c = 0; c < 4; ++c) {     // 4 x ds_read_b32 per frag: 2-way banks
      const u32* p = &bimg[cur * 1280 + c * 320 + rb];
      intx4 v;
      v[0] = (int)p[0]; v[1] = (int)p[1]; v[2] = (int)p[2]; v[3] = (int)p[3];
      bh[c] = v;
    }
#pragma unroll
    for (int ht = 0; ht < 2; ++ht) {
      float gate[4][4];
#pragma unroll
      for (int g = 0; g < 4; ++g) {
        const int F = (g * 2 + ht) * 5;
        intx4 z = {0, 0, 0, 0};
        intx4 ah = __builtin_amdgcn_mfma_i32_16x16x64_i8(wfr[F + 0], bh[0], z, 0, 0, 0);
        ah = __builtin_amdgcn_mfma_i32_16x16x64_i8(wfr[F + 1], bh[1], ah, 0, 0, 0);
        ah = __builtin_amdgcn_mfma_i32_16x16x64_i8(wfr[F + 2], bh[2], ah, 0, 0, 0);
        ah = __builtin_amdgcn_mfma_i32_16x16x64_i8(wfr[F + 3], bh[3], ah, 0, 0, 0);
        intx4 ax = __builtin_amdgcn_mfma_i32_16x16x64_i8(wfr[F + 4], xa, z, 0, 0, 0);
        intx4 a2 = __builtin_amdgcn_mfma_i32_16x16x64_i8(wfr[F + 4], xr, z, 0, 0, 0);
#pragma unroll
        for (int rr = 0; rr < 4; ++rr)
          gate[g][rr] = A_h * (float)ah[rr] + A_x * (float)ax[rr] + A_x2 * (float)a2[rr];
      }
      u32 qw = 0;
      u64 hp = 0;
#pragma unroll
      for (int rr = 0; rr < 4; ++rr) {   // C-layout: n_local=kq*4+rr, batch=l15
        float iv = sigmf(gate[0][rr]);
        float fv = sigmf(gate[1][rr]);
        float gv = tanhfast(gate[2][rr]);
        float ov = sigmf(gate[3][rr]);
        const int ci = ht * 4 + rr;
        float cc = fv * c_st[ci] + iv * gv;
        c_st[ci] = cc;
        float h = ov * tanhfast(cc);
        int q = (int)rintf(h * 127.0f);
        qw |= ((u32)(q & 255)) << (8 * rr);
        hp |= ((u64)f2b(h)) << (16 * rr);
      }
      bimg[nxt * 1280 + wi[ht]] = qw;
      h64[ht] = hp;
    }
    xa = xaN;
    xr = xrN;
    __syncthreads();
  }
  *(u64*)(hsp + (size_t)(TT - 1) * 256) = h64[0];
  *(u64*)(hsp + (size_t)(TT - 1) * 256 + 16) = h64[1];
}

// ---------------- post heads (unchanged, proven) ----------------

__global__ __launch_bounds__(256, 2)
void k_act(const u16* __restrict__ hs, const u16* __restrict__ wafc1,
           const u16* __restrict__ waout, const float* __restrict__ b_afc1,
           const float* __restrict__ b_aout, float* __restrict__ act) {
  __shared__ u16 a_sh[16 * 264];
  __shared__ u16 z_sh[16 * 264];
  __shared__ float sb1[256];
  const int tid = threadIdx.x;
  const int wave = tid >> 6, lane = tid & 63;
  const int l15 = lane & 15, kq = lane >> 4;
  const size_t bt0 = (size_t)blockIdx.x * 16;
  sb1[tid] = b_afc1[tid];
#pragma unroll
  for (int i = 0; i < 2; ++i) {
    int chunk = i * 256 + tid;
    int row = chunk >> 5, c = chunk & 31;
    *(uint4*)&a_sh[row * 264 + c * 8] = *(const uint4*)(hs + (bt0 + row) * 256 + c * 8);
  }
  __syncthreads();
  floatx4 acc[4];
#pragma unroll
  for (int nt = 0; nt < 4; ++nt) acc[nt] = (floatx4){0.f, 0.f, 0.f, 0.f};
#pragma unroll
  for (int kt = 0; kt < 8; ++kt) {
    short8 a = *(const short8*)&a_sh[l15 * 264 + kt * 32 + kq * 8];
#pragma unroll
    for (int nt = 0; nt < 4; ++nt) {
      int n = wave * 64 + nt * 16 + l15;
      short8 b = *(const short8*)(wafc1 + n * 256 + kt * 32 + kq * 8);
      acc[nt] = __builtin_amdgcn_mfma_f32_16x16x32_bf16(a, b, acc[nt], 0, 0, 0);
    }
  }
#pragma unroll
  for (int nt = 0; nt < 4; ++nt) {
    int n = wave * 64 + nt * 16 + l15;
    float bb = sb1[n];
#pragma unroll
    for (int r = 0; r < 4; ++r) {
      float v = acc[nt][r] + bb;
      v = v > 0.f ? v : 0.f;
      z_sh[(kq * 4 + r) * 264 + n] = f2b(v);
    }
  }
  __syncthreads();
  if (wave == 0) {
    floatx4 a2 = (floatx4){0.f, 0.f, 0.f, 0.f};
#pragma unroll
    for (int kt = 0; kt < 8; ++kt) {
      short8 a = *(const short8*)&z_sh[l15 * 264 + kt * 32 + kq * 8];
      short8 b = *(const short8*)(waout + l15 * 256 + kt * 32 + kq * 8);
      a2 = __builtin_amdgcn_mfma_f32_16x16x32_bf16(a, b, a2, 0, 0, 0);
    }
    if (l15 < 8) {
      float bb = b_aout[l15];
#pragma unroll
      for (int r = 0; r < 4; ++r)
        act[(bt0 + (size_t)(kq * 4 + r)) * 8 + l15] = a2[r] + bb;
    }
  }
}

__global__ __launch_bounds__(256, 2)
void k_cb(const u16* __restrict__ hs, const float* __restrict__ x,
          const u16* __restrict__ wcb, const float* __restrict__ b_cont,
          const float* __restrict__ b_bin, float* __restrict__ dout) {
  __shared__ u16 a_sh[16 * 296];
  const int tid = threadIdx.x;
  const int wave = tid >> 6, lane = tid & 63;
  const int l15 = lane & 15, kq = lane >> 4;
  const size_t bt0 = (size_t)blockIdx.x * 16;
#pragma unroll
  for (int i = 0; i < 2; ++i) {
    int chunk = i * 256 + tid;
    int row = chunk >> 5, c = chunk & 31;
    *(uint4*)&a_sh[row * 296 + c * 8] = *(const uint4*)(hs + (bt0 + row) * 256 + c * 8);
  }
  if (tid < 128) {
    int m = tid >> 3, j = tid & 7;
    a_sh[m * 296 + 256 + j] = f2b(x[(bt0 + m) * 43 + 35 + j]);
  }
  for (int i = tid; i < 384; i += 256) {
    int m = i / 24, jj = i % 24;
    a_sh[m * 296 + 264 + jj] = 0;
  }
  __syncthreads();
  const int n = wave * 16 + l15;
  floatx4 acc = (floatx4){0.f, 0.f, 0.f, 0.f};
#pragma unroll
  for (int kt = 0; kt < 9; ++kt) {
    short8 a = *(const short8*)&a_sh[l15 * 296 + kt * 32 + kq * 8];
    short8 b = *(const short8*)(wcb + n * 288 + kt * 32 + kq * 8);
    acc = __builtin_amdgcn_mfma_f32_16x16x32_bf16(a, b, acc, 0, 0, 0);
  }
  if (n < 50) {
    float bb = b_cont[n];
#pragma unroll
    for (int r = 0; r < 4; ++r)
      dout[(bt0 + (size_t)(kq * 4 + r)) * 50 + n] = acc[r] + bb;
  } else if (n < 60) {
    float bb = b_bin[n - 50];
#pragma unroll
    for (int r = 0; r < 4; ++r)
      dout[BIN_OFF + (bt0 + (size_t)(kq * 4 + r)) * 10 + (n - 50)] = sigmf(acc[r] + bb);
  }
}

// ---------------- launch ----------------
extern "C" void kernel_launch(void* const* d_in, const int* in_sizes, int n_in,
                              void* d_out, int out_size, void* d_ws, size_t ws_size,
                              hipStream_t stream) {
  const float* x      = (const float*)d_in[0];
  const float* W_ih   = (const float*)d_in[1];
  const float* W_hh   = (const float*)d_in[2];
  const float* b_ih   = (const float*)d_in[3];
  const float* b_hh   = (const float*)d_in[4];
  const float* W_afc1 = (const float*)d_in[5];
  const float* b_afc1 = (const float*)d_in[6];
  const float* W_aout = (const float*)d_in[7];
  const float* b_aout = (const float*)d_in[8];
  const float* W_cont = (const float*)d_in[9];
  const float* b_cont = (const float*)d_in[10];
  const float* W_bin  = (const float*)d_in[11];
  const float* b_bin  = (const float*)d_in[12];
  float* outf = (float*)d_out;
  char* ws = (char*)d_ws;

  u32*   am     = (u32*)(ws);                    //         64 B
  float* bias   = (float*)(ws + 64);             //      4,096 B
  float* sbuf   = (float*)(ws + 4160);           //         64 B
  int*   wq     = (int*)(ws + 4224);             //    327,680 B
  u16*   wafc1b = (u16*)(ws + 331904);           //    131,072 B
  u16*   waoutb = (u16*)(ws + 462976);           //      8,192 B
  u16*   wcbb   = (u16*)(ws + 471168);           //     36,864 B
  int*   xqb    = (int*)(ws + 524288);           // 16,777,216 B
  u16*   hs     = (u16*)(ws + 17301504);         // 67,108,864 B (end 84,410,368)

  hipLaunchKernelGGL(k_zero4, dim3(1), dim3(64), 0, stream, am);
  hipLaunchKernelGGL(k_amax, dim3(2048), dim3(256), 0, stream, x, W_ih, W_hh, am);
  hipLaunchKernelGGL(k_prep_bias, dim3(4), dim3(256), 0, stream, b_ih, b_hh, bias);
  hipLaunchKernelGGL(k_prep_wq, dim3(320), dim3(256), 0, stream, W_ih, W_hh, bias, am, wq, sbuf);
  hipLaunchKernelGGL(k_prep_xq, dim3(16384), dim3(256), 0, stream, x, am, xqb);
  hipLaunchKernelGGL(k_prep_afc, dim3(272), dim3(256), 0, stream, W_afc1, W_aout, wafc1b, waoutb);
  hipLaunchKernelGGL(k_prep_wcb, dim3(64), dim3(288), 0, stream, W_cont, W_bin, wcbb);
  hipLaunchKernelGGL(k_scan7, dim3(8), dim3(512), 0, stream, wq, xqb, sbuf, hs);
  hipLaunchKernelGGL(k_act, dim3(8192), dim3(256), 0, stream, hs, wafc1b, waoutb, b_afc1, b_aout, outf + ACT_OFF);
  hipLaunchKernelGGL(k_cb, dim3(8192), dim3(256), 0, stream, hs, x, wcbb, b_cont, b_bin, outf);
}

// Round 8
// 1805.503 us; speedup vs baseline: 2.2961x; 2.2961x over previous
//
#include <hip/hip_runtime.h>

typedef unsigned int u32;
typedef unsigned short u16;
typedef unsigned char u8;
typedef unsigned long long u64;
typedef __attribute__((ext_vector_type(8))) short short8;
typedef __attribute__((ext_vector_type(4))) float floatx4;
typedef __attribute__((ext_vector_type(4))) int intx4;

#define TT 1024
#define BIN_OFF 6553600
#define ACT_OFF 7864320

__device__ __forceinline__ u16 f2b(float f) {
  u32 u = __builtin_bit_cast(u32, f);
  u += 0x7fffu + ((u >> 16) & 1u);
  return (u16)(u >> 16);
}
__device__ __forceinline__ float sigm2(float z) {
  return __builtin_amdgcn_rcpf(1.0f + __expf(-z));
}
__device__ __forceinline__ float tanh2(float z) {
  z = fminf(z, 15.0f);
  float e = __expf(2.0f * z);
  return (e - 1.0f) * __builtin_amdgcn_rcpf(e + 1.0f);
}
__device__ __forceinline__ float sigmf(float x) { return 1.0f / (1.0f + __expf(-x)); }
__device__ __forceinline__ float tanhfast(float x) {
  x = fminf(x, 15.0f);
  float e = __expf(2.0f * x);
  return (e - 1.0f) / (e + 1.0f);
}

// ---------------- prep ----------------

__global__ void k_zero4(u32* __restrict__ p) {
  if (threadIdx.x < 4) p[threadIdx.x] = 0;
}
// absmax of x / W_hh / W_ih -> am[0..2].  grid 2048 x 256
__global__ void k_amax(const float* __restrict__ x, const float* __restrict__ wih,
                       const float* __restrict__ whh, u32* __restrict__ am) {
  __shared__ float red[256];
  const int tid = threadIdx.x;
  int b = blockIdx.x;
  const float* src; size_t n; int sec, b0, nb;
  if (b < 1920)      { src = x;   n = 5636096; sec = 0; b0 = 0;    nb = 1920; }
  else if (b < 2016) { src = whh; n = 262144;  sec = 1; b0 = 1920; nb = 96; }
  else               { src = wih; n = 44032;   sec = 2; b0 = 2016; nb = 32; }
  float m = 0.f;
  for (size_t i = (size_t)(b - b0) * 256 + tid; i < n; i += (size_t)nb * 256)
    m = fmaxf(m, fabsf(src[i]));
  red[tid] = m;
  __syncthreads();
  for (int s = 128; s > 0; s >>= 1) {
    if (tid < s) red[tid] = fmaxf(red[tid], red[tid + s]);
    __syncthreads();
  }
  if (tid == 0) atomicMax(&am[sec], __float_as_uint(red[0]));
}
// bias = b_ih + b_hh.  grid 4 x 256
__global__ void k_prep_bias(const float* __restrict__ a, const float* __restrict__ b,
                            float* __restrict__ o) {
  int i = blockIdx.x * 256 + threadIdx.x;
  o[i] = a[i] + b[i];
}
// i8 weight frags. Per wave w: 40 frags, F = tile*5 + c (tile = gate*2+ht;
// c 0..3 h-chunks scale sn_h, c=4 x-chunk scale sn_x, with bias codes at
// k=43 (coarse, unit 127*A_x) and k=44 (fine, unit 127*A_h)).
// A-frag lane l: n = gate*256+w*32+ht*16+(l&15); k = (l>>4)*16 + jq*4 + b.
// grid 320 x 256
__global__ void k_prep_wq2(const float* __restrict__ wih, const float* __restrict__ whh,
                           const float* __restrict__ bias, const u32* __restrict__ am,
                           int* __restrict__ wq, float* __restrict__ sbuf) {
  u32 idx = blockIdx.x * 256 + threadIdx.x;
  const float xmax = fmaxf(__uint_as_float(am[0]), 1e-8f);
  const float whm  = fmaxf(__uint_as_float(am[1]), 1e-8f);
  const float wxm  = fmaxf(__uint_as_float(am[2]), 1e-8f);
  const float sn_h = whm / 127.0f, sn_x = wxm / 127.0f;
  const float sx = xmax / 127.0f;
  const float A_h = sn_h / 127.0f;          // unit of wh_int*h_int and of x-res path
  const float A_x = sn_x * sx;              // unit of wx_int*x_int
  if (idx == 0) { sbuf[0] = A_h; sbuf[1] = A_x; }
  int jq = idx & 3;
  int lane = (idx >> 2) & 63;
  u32 wf = idx >> 8;                        // w*40 + F, < 320
  int F = wf % 40, w = wf / 40;
  int tile = F / 5, c = F % 5;
  int gate = tile >> 1, ht = tile & 1;
  int l15 = lane & 15, kq = lane >> 4;
  int n = gate * 256 + w * 32 + ht * 16 + l15;
  u32 out = 0;
#pragma unroll
  for (int b = 0; b < 4; ++b) {
    int kl = kq * 16 + jq * 4 + b;
    float q = 0.f;
    if (c < 4) {
      q = rintf(whh[n * 256 + c * 64 + kl] / sn_h);
    } else {
      if (kl < 43) q = rintf(wih[n * 43 + kl] / sn_x);
      else if (kl == 43) {
        q = fminf(fmaxf(rintf(bias[n] / (127.0f * A_x)), -127.f), 127.f);
      } else if (kl == 44) {
        float qc = fminf(fmaxf(rintf(bias[n] / (127.0f * A_x)), -127.f), 127.f);
        q = rintf((bias[n] - qc * 127.0f * A_x) / (127.0f * A_h));
      }
    }
    q = fminf(fmaxf(q, -127.f), 127.f);
    int qi = (int)q;
    out |= ((u32)(qi & 255)) << (8 * b);
  }
  wq[idx] = (int)out;
}
// dense i8 x-images, R=2 rows/WG: per (bg,t) 64 dwords:
// dw 0..31 main (row r at r*16+kd, scale sx), dw 32..63 residual (scale
// sr = A_h/sn_x). byte k = kd*4+b; k<35: x[t]; 35..42: x[t-1]; 43: bias-coarse
// slot (main 127 / res 0); 44: bias-fine slot (main 0 / res 127).
// grid 16384 x 256 (4,194,304 dwords)
__global__ void k_prep_xq2(const float* __restrict__ x, const u32* __restrict__ am,
                           int* __restrict__ xq) {
  u32 idx = blockIdx.x * 256 + threadIdx.x;
  const float xmax = fmaxf(__uint_as_float(am[0]), 1e-8f);
  const float whm  = fmaxf(__uint_as_float(am[1]), 1e-8f);
  const float wxm  = fmaxf(__uint_as_float(am[2]), 1e-8f);
  const float sx = xmax / 127.0f;
  const float sr = whm / (127.0f * wxm);    // A_h / sn_x
  u32 unit = idx >> 6;                      // bg*1024 + t
  u32 rem = idx & 63;
  int res = rem >> 5, r = (rem >> 4) & 1, kd = rem & 15;
  int bg = unit >> 10, t = unit & 1023;
  int row = bg * 2 + r;
  u32 out = 0;
#pragma unroll
  for (int b = 0; b < 4; ++b) {
    int k = kd * 4 + b;
    int q = 0;
    if (k < 43) {
      float xv = 0.f;
      if (k < 35) xv = x[((size_t)row * TT + t) * 43 + k];
      else if (t > 0) xv = x[((size_t)row * TT + (t - 1)) * 43 + k];
      float q1 = fminf(fmaxf(rintf(xv / sx), -127.f), 127.f);
      if (!res) q = (int)q1;
      else q = (int)fminf(fmaxf(rintf((xv - sx * q1) / sr), -127.f), 127.f);
    } else if (k == 43) q = res ? 0 : 127;
    else if (k == 44) q = res ? 127 : 0;
    out |= ((u32)(q & 255)) << (8 * b);
  }
  xq[idx] = (int)out;
}
// W_afc1 (256x256) and W_aout padded to 16x256.  grid 272 x 256
__global__ void k_prep_afc(const float* __restrict__ wafc1, const float* __restrict__ waout,
                           u16* __restrict__ ob1, u16* __restrict__ ob2) {
  int r = blockIdx.x, k = threadIdx.x;
  if (r < 256) ob1[r * 256 + k] = f2b(wafc1[r * 256 + k]);
  else {
    int y = r - 256;
    ob2[y * 256 + k] = f2b(y < 8 ? waout[y * 256 + k] : 0.f);
  }
}
// Wcb[64][288].  grid 64 x 288
__global__ void k_prep_wcb(const float* __restrict__ wcont, const float* __restrict__ wbin,
                           u16* __restrict__ o) {
  int nrow = blockIdx.x, k = threadIdx.x;
  float v = 0.f;
  if (k < 264) {
    if (nrow < 50) v = wcont[nrow * 264 + k];
    else if (nrow < 60) v = wbin[(nrow - 50) * 264 + k];
  }
  o[nrow * 288 + k] = f2b(v);
}

// ---------------- LSTM scan v8: i8, R=2 rows/WG, 64 WGs ----------------
// 64 WGs x 512 thr; WG bg owns batch rows {2bg, 2bg+1}, all 1024 gate cols.
// Self-contained (no inter-WG traffic). Per step:
//   read swizzled i8 h-image (bimg[cur]) as B-frags -> 48 MFMA/wave
//   (AH chain: 4 h-chunks + x-residual at matched scale A_h; AX: x-main)
//   -> combine 2 cvt+mul+fma -> valid lanes (l15<2) write gates to gimg
//   -> B1 -> each thread processes exactly ONE cell (r=tid>>8,col=tid&255):
//   activations via rcp (no f32 division), c/h update, i8 h byte -> bimg[nxt],
//   bf16 h kept for deferred coalesced hs store -> B2.
__global__ __launch_bounds__(512, 2)
void k_scan8(const int* wq_, const int* __restrict__ xqd,
             const float* __restrict__ sb, u16* __restrict__ hs) {
  __shared__ u8 bimg[2 * 4096];     // swizzled i8 h image (rows 2..15 stay 0)
  __shared__ float gimg[8 * 260];   // [ (r*4+g)*260 + col ]
  const int tid = threadIdx.x;
  const int w = tid >> 6, lane = tid & 63;
  const int l15 = lane & 15, kq = lane >> 4;
  const int bg = blockIdx.x;

  *(uint4*)&bimg[tid * 16] = (uint4){0, 0, 0, 0};

  intx4 wfr[40];
  {
    const intx4* wp = (const intx4*)wq_ + (size_t)(w * 40) * 64 + lane;
#pragma unroll
    for (int F = 0; F < 40; ++F) wfr[F] = wp[(size_t)F * 64];
  }
  const float A_h = sb[0], A_x = sb[1];

  const int* xu = xqd + (size_t)bg * 1024 * 64;
  const int xo = l15 * 16 + kq * 4;
  intx4 xa = *(const intx4*)(xu + xo);
  intx4 xr = *(const intx4*)(xu + 32 + xo);

  const int wcol = w * 32 + kq * 4;      // + ht*16 + rr
  const int r = tid >> 8, col = tid & 255;
  const int bwr = r * 256 + (((col >> 4) ^ r) << 4) + (col & 15);
  u16* hgp = hs + ((size_t)(bg * 2 + r) * TT) * 256 + col;

  float c_st = 0.f;
  u16 h16 = 0;
  __syncthreads();

  for (int t = 0; t < TT; ++t) {
    const int cur = t & 1, nxt = cur ^ 1;
    if (t > 0) hgp[(size_t)(t - 1) * 256] = h16;     // deferred coalesced hs store
    intx4 xaN = xa, xrN = xr;
    if (t + 1 < TT) {                                // prefetch next x frags
      xaN = *(const intx4*)(xu + (size_t)(t + 1) * 64 + xo);
      xrN = *(const intx4*)(xu + (size_t)(t + 1) * 64 + 32 + xo);
    }
    intx4 bh[4];
#pragma unroll
    for (int c = 0; c < 4; ++c)                      // swizzled: 2-way banks (free)
      bh[c] = *(const intx4*)&bimg[cur * 4096 + l15 * 256 +
                                   ((((c * 4 + kq) ^ l15) & 15) << 4)];
#pragma unroll
    for (int ht = 0; ht < 2; ++ht) {
      intx4 AH[4], AX[4];
#pragma unroll
      for (int g = 0; g < 4; ++g) {
        const int F = (g * 2 + ht) * 5;
        intx4 z = {0, 0, 0, 0};
        intx4 a = __builtin_amdgcn_mfma_i32_16x16x64_i8(wfr[F + 0], bh[0], z, 0, 0, 0);
        a = __builtin_amdgcn_mfma_i32_16x16x64_i8(wfr[F + 1], bh[1], a, 0, 0, 0);
        a = __builtin_amdgcn_mfma_i32_16x16x64_i8(wfr[F + 2], bh[2], a, 0, 0, 0);
        a = __builtin_amdgcn_mfma_i32_16x16x64_i8(wfr[F + 3], bh[3], a, 0, 0, 0);
        AH[g] = __builtin_amdgcn_mfma_i32_16x16x64_i8(wfr[F + 4], xr, a, 0, 0, 0);
        AX[g] = __builtin_amdgcn_mfma_i32_16x16x64_i8(wfr[F + 4], xa, z, 0, 0, 0);
      }
#pragma unroll
      for (int g = 0; g < 4; ++g) {
#pragma unroll
        for (int rr = 0; rr < 4; ++rr) {
          float gp = A_h * (float)AH[g][rr] + A_x * (float)AX[g][rr];
          if (l15 < 2)
            gimg[(l15 * 4 + g) * 260 + wcol + ht * 16 + rr] = gp;
        }
      }
    }
    __syncthreads();  // B1: gimg complete
    float g0 = gimg[(r * 4 + 0) * 260 + col];
    float g1 = gimg[(r * 4 + 1) * 260 + col];
    float g2 = gimg[(r * 4 + 2) * 260 + col];
    float g3 = gimg[(r * 4 + 3) * 260 + col];
    float iv = sigm2(g0);
    float fv = sigm2(g1);
    float gv = tanh2(g2);
    float ov = sigm2(g3);
    float cc = fv * c_st + iv * gv;
    c_st = cc;
    float h = ov * tanh2(cc);
    int q = (int)rintf(h * 127.0f);
    bimg[nxt * 4096 + bwr] = (u8)q;
    h16 = f2b(h);
    xa = xaN;
    xr = xrN;
    __syncthreads();  // B2: bimg[nxt] complete
  }
  hgp[(size_t)(TT - 1) * 256] = h16;
}

// ---------------- post heads (unchanged, proven) ----------------

__global__ __launch_bounds__(256, 2)
void k_act(const u16* __restrict__ hs, const u16* __restrict__ wafc1,
           const u16* __restrict__ waout, const float* __restrict__ b_afc1,
           const float* __restrict__ b_aout, float* __restrict__ act) {
  __shared__ u16 a_sh[16 * 264];
  __shared__ u16 z_sh[16 * 264];
  __shared__ float sb1[256];
  const int tid = threadIdx.x;
  const int wave = tid >> 6, lane = tid & 63;
  const int l15 = lane & 15, kq = lane >> 4;
  const size_t bt0 = (size_t)blockIdx.x * 16;
  sb1[tid] = b_afc1[tid];
#pragma unroll
  for (int i = 0; i < 2; ++i) {
    int chunk = i * 256 + tid;
    int row = chunk >> 5, c = chunk & 31;
    *(uint4*)&a_sh[row * 264 + c * 8] = *(const uint4*)(hs + (bt0 + row) * 256 + c * 8);
  }
  __syncthreads();
  floatx4 acc[4];
#pragma unroll
  for (int nt = 0; nt < 4; ++nt) acc[nt] = (floatx4){0.f, 0.f, 0.f, 0.f};
#pragma unroll
  for (int kt = 0; kt < 8; ++kt) {
    short8 a = *(const short8*)&a_sh[l15 * 264 + kt * 32 + kq * 8];
#pragma unroll
    for (int nt = 0; nt < 4; ++nt) {
      int n = wave * 64 + nt * 16 + l15;
      short8 b = *(const short8*)(wafc1 + n * 256 + kt * 32 + kq * 8);
      acc[nt] = __builtin_amdgcn_mfma_f32_16x16x32_bf16(a, b, acc[nt], 0, 0, 0);
    }
  }
#pragma unroll
  for (int nt = 0; nt < 4; ++nt) {
    int n = wave * 64 + nt * 16 + l15;
    float bb = sb1[n];
#pragma unroll
    for (int r = 0; r < 4; ++r) {
      float v = acc[nt][r] + bb;
      v = v > 0.f ? v : 0.f;
      z_sh[(kq * 4 + r) * 264 + n] = f2b(v);
    }
  }
  __syncthreads();
  if (wave == 0) {
    floatx4 a2 = (floatx4){0.f, 0.f, 0.f, 0.f};
#pragma unroll
    for (int kt = 0; kt < 8; ++kt) {
      short8 a = *(const short8*)&z_sh[l15 * 264 + kt * 32 + kq * 8];
      short8 b = *(const short8*)(waout + l15 * 256 + kt * 32 + kq * 8);
      a2 = __builtin_amdgcn_mfma_f32_16x16x32_bf16(a, b, a2, 0, 0, 0);
    }
    if (l15 < 8) {
      float bb = b_aout[l15];
#pragma unroll
      for (int r = 0; r < 4; ++r)
        act[(bt0 + (size_t)(kq * 4 + r)) * 8 + l15] = a2[r] + bb;
    }
  }
}

__global__ __launch_bounds__(256, 2)
void k_cb(const u16* __restrict__ hs, const float* __restrict__ x,
          const u16* __restrict__ wcb, const float* __restrict__ b_cont,
          const float* __restrict__ b_bin, float* __restrict__ dout) {
  __shared__ u16 a_sh[16 * 296];
  const int tid = threadIdx.x;
  const int wave = tid >> 6, lane = tid & 63;
  const int l15 = lane & 15, kq = lane >> 4;
  const size_t bt0 = (size_t)blockIdx.x * 16;
#pragma unroll
  for (int i = 0; i < 2; ++i) {
    int chunk = i * 256 + tid;
    int row = chunk >> 5, c = chunk & 31;
    *(uint4*)&a_sh[row * 296 + c * 8] = *(const uint4*)(hs + (bt0 + row) * 256 + c * 8);
  }
  if (tid < 128) {
    int m = tid >> 3, j = tid & 7;
    a_sh[m * 296 + 256 + j] = f2b(x[(bt0 + m) * 43 + 35 + j]);
  }
  for (int i = tid; i < 384; i += 256) {
    int m = i / 24, jj = i % 24;
    a_sh[m * 296 + 264 + jj] = 0;
  }
  __syncthreads();
  const int n = wave * 16 + l15;
  floatx4 acc = (floatx4){0.f, 0.f, 0.f, 0.f};
#pragma unroll
  for (int kt = 0; kt < 9; ++kt) {
    short8 a = *(const short8*)&a_sh[l15 * 296 + kt * 32 + kq * 8];
    short8 b = *(const short8*)(wcb + n * 288 + kt * 32 + kq * 8);
    acc = __builtin_amdgcn_mfma_f32_16x16x32_bf16(a, b, acc, 0, 0, 0);
  }
  if (n < 50) {
    float bb = b_cont[n];
#pragma unroll
    for (int r = 0; r < 4; ++r)
      dout[(bt0 + (size_t)(kq * 4 + r)) * 50 + n] = acc[r] + bb;
  } else if (n < 60) {
    float bb = b_bin[n - 50];
#pragma unroll
    for (int r = 0; r < 4; ++r)
      dout[BIN_OFF + (bt0 + (size_t)(kq * 4 + r)) * 10 + (n - 50)] = sigmf(acc[r] + bb);
  }
}

// ---------------- launch ----------------
extern "C" void kernel_launch(void* const* d_in, const int* in_sizes, int n_in,
                              void* d_out, int out_size, void* d_ws, size_t ws_size,
                              hipStream_t stream) {
  const float* x      = (const float*)d_in[0];
  const float* W_ih   = (const float*)d_in[1];
  const float* W_hh   = (const float*)d_in[2];
  const float* b_ih   = (const float*)d_in[3];
  const float* b_hh   = (const float*)d_in[4];
  const float* W_afc1 = (const float*)d_in[5];
  const float* b_afc1 = (const float*)d_in[6];
  const float* W_aout = (const float*)d_in[7];
  const float* b_aout = (const float*)d_in[8];
  const float* W_cont = (const float*)d_in[9];
  const float* b_cont = (const float*)d_in[10];
  const float* W_bin  = (const float*)d_in[11];
  const float* b_bin  = (const float*)d_in[12];
  float* outf = (float*)d_out;
  char* ws = (char*)d_ws;

  u32*   am     = (u32*)(ws);                    //         64 B
  float* bias   = (float*)(ws + 64);             //      4,096 B
  float* sbuf   = (float*)(ws + 4160);           //         64 B
  int*   wq     = (int*)(ws + 4224);             //    327,680 B
  u16*   wafc1b = (u16*)(ws + 331904);           //    131,072 B
  u16*   waoutb = (u16*)(ws + 462976);           //      8,192 B
  u16*   wcbb   = (u16*)(ws + 471168);           //     36,864 B
  int*   xqd    = (int*)(ws + 524288);           // 16,777,216 B (+4K pad)
  u16*   hs     = (u16*)(ws + 17305600);         // 67,108,864 B (end 84,414,464)

  hipLaunchKernelGGL(k_zero4, dim3(1), dim3(64), 0, stream, am);
  hipLaunchKernelGGL(k_amax, dim3(2048), dim3(256), 0, stream, x, W_ih, W_hh, am);
  hipLaunchKernelGGL(k_prep_bias, dim3(4), dim3(256), 0, stream, b_ih, b_hh, bias);
  hipLaunchKernelGGL(k_prep_wq2, dim3(320), dim3(256), 0, stream, W_ih, W_hh, bias, am, wq, sbuf);
  hipLaunchKernelGGL(k_prep_xq2, dim3(16384), dim3(256), 0, stream, x, am, xqd);
  hipLaunchKernelGGL(k_prep_afc, dim3(272), dim3(256), 0, stream, W_afc1, W_aout, wafc1b, waoutb);
  hipLaunchKernelGGL(k_prep_wcb, dim3(64), dim3(288), 0, stream, W_cont, W_bin, wcbb);
  hipLaunchKernelGGL(k_scan8, dim3(64), dim3(512), 0, stream, wq, xqd, sbuf, hs);
  hipLaunchKernelGGL(k_act, dim3(8192), dim3(256), 0, stream, hs, wafc1b, waoutb, b_afc1, b_aout, outf + ACT_OFF);
  hipLaunchKernelGGL(k_cb, dim3(8192), dim3(256), 0, stream, hs, x, wcbb, b_cont, b_bin, outf);
}